// Round 9
// baseline (185.874 us; speedup 1.0000x reference)
//
#include <hip/hip_runtime.h>

// Problem constants (B=8, Tq=Tv=512, D=512, U=128)
constexpr int Bb = 8;
constexpr int Tq = 512;
constexpr int Tv = 512;
constexpr int Dd = 512;
constexpr int Uu = 128;
constexpr float C2LOG2E = 2.88539008177792681f;   // 2*log2(e)
constexpr float LOG2E   = 1.44269504088896341f;

// ---------------------------------------------------------------------------
// Kernel A: projections (R5 structure — best measured). 16 rows/block, 256
// threads, 512 blocks. Thread: ub=t&63 -> u in {ub, ub+64}; rh=t>>6 -> rows
// rh*4..rh*4+3.  q half -> qf2[row][u] row-major; k half -> kT[b][u][j]
// (transposed, direct scattered stores). Both premultiplied by 2*log2e.
// ---------------------------------------------------------------------------
__global__ __launch_bounds__(256) void proj_kernel(
    const float* __restrict__ query,
    const float* __restrict__ key,
    const float* __restrict__ Wa,
    const float* __restrict__ Ua,
    float* __restrict__ qf2, float* __restrict__ kT)
{
    const int R    = blockIdx.x * 16;              // 0..8191
    const bool isQ = R < Bb * Tq;
    const float* __restrict__ src = isQ ? query : key;
    const float* __restrict__ W   = isQ ? Wa : Ua;
    const int Rloc = isQ ? R : R - Bb * Tq;        // 0..4095

    __shared__ float x[16 * Dd];                   // 32 KB
    const int t = threadIdx.x;

    {   // stage 16 rows: 2048 float4, coalesced
        const float4* __restrict__ s4 =
            reinterpret_cast<const float4*>(src + (size_t)Rloc * Dd);
        float4* x4 = reinterpret_cast<float4*>(x);
#pragma unroll
        for (int m = 0; m < 8; ++m) x4[t + 256 * m] = s4[t + 256 * m];
    }
    __syncthreads();

    const int ub = t & 63;
    const int rh = t >> 6;                         // 0..3
    float acc[4][2] = {{0,0},{0,0},{0,0},{0,0}};

#pragma unroll 2
    for (int d4 = 0; d4 < Dd / 4; ++d4) {
        const int d = d4 * 4;
        const float w0x = W[(d + 0) * Uu + ub],      w1x = W[(d + 0) * Uu + ub + 64];
        const float w0y = W[(d + 1) * Uu + ub],      w1y = W[(d + 1) * Uu + ub + 64];
        const float w0z = W[(d + 2) * Uu + ub],      w1z = W[(d + 2) * Uu + ub + 64];
        const float w0w = W[(d + 3) * Uu + ub],      w1w = W[(d + 3) * Uu + ub + 64];
#pragma unroll
        for (int k = 0; k < 4; ++k) {
            const float4 xv = *reinterpret_cast<const float4*>(x + (rh * 4 + k) * Dd + d);
            acc[k][0] = fmaf(xv.x, w0x, acc[k][0]);
            acc[k][0] = fmaf(xv.y, w0y, acc[k][0]);
            acc[k][0] = fmaf(xv.z, w0z, acc[k][0]);
            acc[k][0] = fmaf(xv.w, w0w, acc[k][0]);
            acc[k][1] = fmaf(xv.x, w1x, acc[k][1]);
            acc[k][1] = fmaf(xv.y, w1y, acc[k][1]);
            acc[k][1] = fmaf(xv.z, w1z, acc[k][1]);
            acc[k][1] = fmaf(xv.w, w1w, acc[k][1]);
        }
    }

    if (isQ) {
#pragma unroll
        for (int k = 0; k < 4; ++k) {
            const size_t row = (size_t)(Rloc + rh * 4 + k);
            qf2[row * Uu + ub]      = C2LOG2E * acc[k][0];
            qf2[row * Uu + ub + 64] = C2LOG2E * acc[k][1];
        }
    } else {
        const int b  = Rloc >> 9;
        const int j0 = Rloc & 511;
        float* __restrict__ kb = kT + (size_t)b * Uu * Tv;
#pragma unroll
        for (int k = 0; k < 4; ++k) {
            const int j = j0 + rh * 4 + k;
            kb[(size_t)ub        * Tv + j] = C2LOG2E * acc[k][0];
            kb[(size_t)(ub + 64) * Tv + j] = C2LOG2E * acc[k][1];
        }
    }
}

// ---------------------------------------------------------------------------
// Kernel B: attention, 8 query rows/block, 1024 threads (16 waves), 512
// blocks -> 2 blocks/CU = 32 waves/CU (100% occupancy cap).
//   score : j=t&511, ih=t>>9 -> rows ih*4..ih*4+3 (acc[4]).
//           w[i][j] = mask ? -2*sum_u scale_u*rcp(1+exp2(q2+k2)) : -1e9
//   softmax: 16 waves; wave wv -> row wv>>1, half wv&1; 2-stage combine.
//   context: group g=t>>8 (0..3) owns j-quarter [g*128,(g+1)*128);
//            c=t&255 -> d pair d0=2c; all 8 rows in registers; groups 1..3
//            dump partials to LDS, group 0 combines + writes.
// ---------------------------------------------------------------------------
__global__ __launch_bounds__(1024, 8) void attn_kernel(
    const float* __restrict__ qf2, const float* __restrict__ kT,
    const float* __restrict__ value,
    const int* __restrict__ mask,
    const float* __restrict__ scale,
    float* __restrict__ out)
{
    const int r0 = blockIdx.x * 8;            // first query row (0..4095)
    const int b  = r0 >> 9;
    const int t  = threadIdx.x;               // 0..1023

    __shared__ float q2[8 * Uu];              // 4 KB
    __shared__ float s2[Uu];                  // 0.5 KB
    __shared__ float w[8 * Tv];               // 16 KB
    __shared__ float pbuf[3 * 8 * Dd];        // 48 KB
    __shared__ float pmax[16];
    __shared__ float psum[16];

    const int j  = t & 511;
    const int ih = t >> 9;                    // 0/1 (wave-uniform)
    const int mk = mask[b * Tv + j];

    if (t < 256)
        reinterpret_cast<float4*>(q2)[t] =
            reinterpret_cast<const float4*>(qf2 + (size_t)r0 * Uu)[t];
    else if (t < 384) s2[t - 256] = scale[t - 256];
    __syncthreads();

    // ---- scores ----
    const float* __restrict__ kb = kT + (size_t)b * Uu * Tv + j;
    const float* __restrict__ qh = q2 + ih * 4 * Uu;
    float acc[4] = {0, 0, 0, 0};
#pragma unroll 2
    for (int u4 = 0; u4 < Uu / 4; ++u4) {
        const float kx = kb[(size_t)(u4 * 4 + 0) * Tv];
        const float ky = kb[(size_t)(u4 * 4 + 1) * Tv];
        const float kz = kb[(size_t)(u4 * 4 + 2) * Tv];
        const float kw = kb[(size_t)(u4 * 4 + 3) * Tv];
        const float4 sv = reinterpret_cast<const float4*>(s2)[u4];
#pragma unroll
        for (int i = 0; i < 4; ++i) {
            const float4 qv = *reinterpret_cast<const float4*>(qh + i * Uu + u4 * 4);
            float e0 = __builtin_amdgcn_exp2f(qv.x + kx);
            float e1 = __builtin_amdgcn_exp2f(qv.y + ky);
            float e2 = __builtin_amdgcn_exp2f(qv.z + kz);
            float e3 = __builtin_amdgcn_exp2f(qv.w + kw);
            acc[i] = fmaf(sv.x, __builtin_amdgcn_rcpf(e0 + 1.f), acc[i]);
            acc[i] = fmaf(sv.y, __builtin_amdgcn_rcpf(e1 + 1.f), acc[i]);
            acc[i] = fmaf(sv.z, __builtin_amdgcn_rcpf(e2 + 1.f), acc[i]);
            acc[i] = fmaf(sv.w, __builtin_amdgcn_rcpf(e3 + 1.f), acc[i]);
        }
    }
#pragma unroll
    for (int i = 0; i < 4; ++i)
        w[(ih * 4 + i) * Tv + j] = mk ? (-2.f * acc[i]) : -1e9f;
    __syncthreads();

    // ---- softmax: wave wv -> row wv>>1, column half wv&1 ----
    {
        const int wv = t >> 6, ln = t & 63;
        const int row = wv >> 1, half = wv & 1;
        float* __restrict__ rw = w + row * Tv + half * 256;
        float vals[4];
        float m = -3e38f;
#pragma unroll
        for (int c = 0; c < 4; ++c) { vals[c] = rw[ln + 64 * c]; m = fmaxf(m, vals[c]); }
#pragma unroll
        for (int off = 32; off; off >>= 1) m = fmaxf(m, __shfl_xor(m, off, 64));
        if (ln == 0) pmax[wv] = m;
        __syncthreads();
        m = fmaxf(pmax[row * 2], pmax[row * 2 + 1]);
        float sum = 0.f;
#pragma unroll
        for (int c = 0; c < 4; ++c) {
            float e = __builtin_amdgcn_exp2f((vals[c] - m) * LOG2E);
            rw[ln + 64 * c] = e;
            sum += e;
        }
#pragma unroll
        for (int off = 32; off; off >>= 1) sum += __shfl_xor(sum, off, 64);
        if (ln == 0) psum[wv] = sum;
    }
    __syncthreads();

    // ---- context: group g owns j-quarter, all 8 rows, d-pair per thread ----
    const int g  = t >> 8;                 // 0..3
    const int c  = t & 255;
    const int d0 = c * 2;
    const int jb = g * 128;
    const float* __restrict__ vb = value + (size_t)b * Tv * Dd + d0;
    float ax[8], ay[8];
#pragma unroll
    for (int i = 0; i < 8; ++i) { ax[i] = 0.f; ay[i] = 0.f; }

#pragma unroll 2
    for (int j4 = 0; j4 < 32; ++j4) {
        const int jj = jb + j4 * 4;
        const float2 v0 = *reinterpret_cast<const float2*>(vb + (size_t)(jj + 0) * Dd);
        const float2 v1 = *reinterpret_cast<const float2*>(vb + (size_t)(jj + 1) * Dd);
        const float2 v2 = *reinterpret_cast<const float2*>(vb + (size_t)(jj + 2) * Dd);
        const float2 v3 = *reinterpret_cast<const float2*>(vb + (size_t)(jj + 3) * Dd);
#pragma unroll
        for (int i = 0; i < 8; ++i) {
            const float4 wq = *reinterpret_cast<const float4*>(w + i * Tv + jj); // broadcast
            ax[i] = fmaf(wq.x, v0.x, ax[i]); ay[i] = fmaf(wq.x, v0.y, ay[i]);
            ax[i] = fmaf(wq.y, v1.x, ax[i]); ay[i] = fmaf(wq.y, v1.y, ay[i]);
            ax[i] = fmaf(wq.z, v2.x, ax[i]); ay[i] = fmaf(wq.z, v2.y, ay[i]);
            ax[i] = fmaf(wq.w, v3.x, ax[i]); ay[i] = fmaf(wq.w, v3.y, ay[i]);
        }
    }

    if (g != 0) {
#pragma unroll
        for (int i = 0; i < 8; ++i) {
            float2 p; p.x = ax[i]; p.y = ay[i];
            *reinterpret_cast<float2*>(pbuf + ((g - 1) * 8 + i) * Dd + d0) = p;
        }
    }
    __syncthreads();
    if (g == 0) {
#pragma unroll
        for (int i = 0; i < 8; ++i) {
            const float inv = 1.0f / (psum[2 * i] + psum[2 * i + 1]);
            const float2 p1 = *reinterpret_cast<const float2*>(pbuf + (0 * 8 + i) * Dd + d0);
            const float2 p2 = *reinterpret_cast<const float2*>(pbuf + (1 * 8 + i) * Dd + d0);
            const float2 p3 = *reinterpret_cast<const float2*>(pbuf + (2 * 8 + i) * Dd + d0);
            float2 o;
            o.x = (ax[i] + p1.x + p2.x + p3.x) * inv;
            o.y = (ay[i] + p1.y + p2.y + p3.y) * inv;
            *reinterpret_cast<float2*>(out + (size_t)(r0 + i) * Dd + d0) = o;
        }
    }
}

extern "C" void kernel_launch(void* const* d_in, const int* in_sizes, int n_in,
                              void* d_out, int out_size, void* d_ws, size_t ws_size,
                              hipStream_t stream)
{
    const float* query = (const float*)d_in[0];
    const float* key   = (const float*)d_in[1];
    const float* value = (const float*)d_in[2];
    const int*   mask  = (const int*)d_in[3];     // proven int32 (R2 bit-identical)
    const float* Wa    = (const float*)d_in[4];
    const float* Ua    = (const float*)d_in[5];
    const float* scale = (const float*)d_in[6];
    float* out = (float*)d_out;

    float* qf2 = (float*)d_ws;                    // [4096,128] = 2 MB (premult)
    float* kT  = qf2 + Bb * Tq * Uu;              // [8][128][512] = 2 MB (premult, transposed)

    proj_kernel<<<(2 * Bb * Tq) / 16, 256, 0, stream>>>(query, key, Wa, Ua, qf2, kT);
    attn_kernel<<<(Bb * Tq) / 8, 1024, 0, stream>>>(qf2, kT, value, mask, scale, out);
}

// Round 10
// 169.142 us; speedup vs baseline: 1.0989x; 1.0989x over previous
//
#include <hip/hip_runtime.h>

// Problem constants (B=8, Tq=Tv=512, D=512, U=128)
constexpr int Bb = 8;
constexpr int Tq = 512;
constexpr int Tv = 512;
constexpr int Dd = 512;
constexpr int Uu = 128;
constexpr float C2LOG2E = 2.88539008177792681f;   // 2*log2(e)
constexpr float LOG2E   = 1.44269504088896341f;

// ---------------------------------------------------------------------------
// Kernel C: per-batch mask compaction. 1 block, 512 threads; wave wv owns
// batch wv. jidx[b][jc] = original j of compact slot jc (0-padded),
// posArr[b][j] = compact slot or -1, cntArr[b] = #valid.
// Exactly equivalent to -1e9 masking: masked keys get weight exp(-1e9-m)=0.
// ---------------------------------------------------------------------------
__global__ __launch_bounds__(512) void compact_kernel(
    const int* __restrict__ mask, int* __restrict__ jidx,
    int* __restrict__ posArr, int* __restrict__ cntArr)
{
    const int wv = threadIdx.x >> 6;          // batch
    const int ln = threadIdx.x & 63;
#pragma unroll
    for (int c = 0; c < 8; ++c) jidx[wv * 512 + c * 64 + ln] = 0;  // pad-init
    int base = 0;
#pragma unroll
    for (int c = 0; c < 8; ++c) {
        const int j = c * 64 + ln;
        const int v = (mask[wv * 512 + j] != 0);
        const unsigned long long bits = __ballot(v);
        const int pos = base + (int)__popcll(bits & ((1ull << ln) - 1ull));
        if (v) jidx[wv * 512 + pos] = j;
        posArr[wv * 512 + j] = v ? pos : -1;
        base += (int)__popcll(bits);
    }
    if (ln == 0) cntArr[wv] = base;
}

// ---------------------------------------------------------------------------
// Kernel A: projections (R5 structure — best measured). 16 rows/block, 256
// threads, 512 blocks. q half -> qf2[row][u] row-major; k half -> compact
// kT[b][u][pos[j]] (masked rows skipped). Both premultiplied by 2*log2e.
// ---------------------------------------------------------------------------
__global__ __launch_bounds__(256) void proj_kernel(
    const float* __restrict__ query,
    const float* __restrict__ key,
    const float* __restrict__ Wa,
    const float* __restrict__ Ua,
    const int* __restrict__ posArr,
    float* __restrict__ qf2, float* __restrict__ kT)
{
    const int R    = blockIdx.x * 16;              // 0..8191
    const bool isQ = R < Bb * Tq;
    const float* __restrict__ src = isQ ? query : key;
    const float* __restrict__ W   = isQ ? Wa : Ua;
    const int Rloc = isQ ? R : R - Bb * Tq;        // 0..4095

    __shared__ float x[16 * Dd];                   // 32 KB
    const int t = threadIdx.x;

    {   // stage 16 rows: 2048 float4, coalesced
        const float4* __restrict__ s4 =
            reinterpret_cast<const float4*>(src + (size_t)Rloc * Dd);
        float4* x4 = reinterpret_cast<float4*>(x);
#pragma unroll
        for (int m = 0; m < 8; ++m) x4[t + 256 * m] = s4[t + 256 * m];
    }
    __syncthreads();

    const int ub = t & 63;
    const int rh = t >> 6;                         // 0..3
    float acc[4][2] = {{0,0},{0,0},{0,0},{0,0}};

#pragma unroll 2
    for (int d4 = 0; d4 < Dd / 4; ++d4) {
        const int d = d4 * 4;
        const float w0x = W[(d + 0) * Uu + ub],      w1x = W[(d + 0) * Uu + ub + 64];
        const float w0y = W[(d + 1) * Uu + ub],      w1y = W[(d + 1) * Uu + ub + 64];
        const float w0z = W[(d + 2) * Uu + ub],      w1z = W[(d + 2) * Uu + ub + 64];
        const float w0w = W[(d + 3) * Uu + ub],      w1w = W[(d + 3) * Uu + ub + 64];
#pragma unroll
        for (int k = 0; k < 4; ++k) {
            const float4 xv = *reinterpret_cast<const float4*>(x + (rh * 4 + k) * Dd + d);
            acc[k][0] = fmaf(xv.x, w0x, acc[k][0]);
            acc[k][0] = fmaf(xv.y, w0y, acc[k][0]);
            acc[k][0] = fmaf(xv.z, w0z, acc[k][0]);
            acc[k][0] = fmaf(xv.w, w0w, acc[k][0]);
            acc[k][1] = fmaf(xv.x, w1x, acc[k][1]);
            acc[k][1] = fmaf(xv.y, w1y, acc[k][1]);
            acc[k][1] = fmaf(xv.z, w1z, acc[k][1]);
            acc[k][1] = fmaf(xv.w, w1w, acc[k][1]);
        }
    }

    if (isQ) {
#pragma unroll
        for (int k = 0; k < 4; ++k) {
            const size_t row = (size_t)(Rloc + rh * 4 + k);
            qf2[row * Uu + ub]      = C2LOG2E * acc[k][0];
            qf2[row * Uu + ub + 64] = C2LOG2E * acc[k][1];
        }
    } else {
        float* __restrict__ kb = kT + (size_t)(Rloc >> 9) * Uu * Tv;
#pragma unroll
        for (int k = 0; k < 4; ++k) {
            const int row = Rloc + rh * 4 + k;     // == b*512 + j
            const int p   = posArr[row];
            if (p >= 0) {
                kb[(size_t)ub        * Tv + p] = C2LOG2E * acc[k][0];
                kb[(size_t)(ub + 64) * Tv + p] = C2LOG2E * acc[k][1];
            }
        }
    }
}

// ---------------------------------------------------------------------------
// Kernel B: attention over COMPACT keys. 8 query rows/block, 512 threads,
// 512 blocks (R8 shape).
//   score : thread t <-> compact key jc=t (only jc<cnt active); acc[8].
//           w[i][jc] = -2*sum_u scale_u*rcp(1+exp2(q2+k2));  idle slots -> 0.
//   softmax: wave wv -> row wv, over [0,cnt) only.
//   context: group g (0/1) owns a 4-aligned compact j-range; value rows via
//            jidx indirection; partials combined via LDS.
// ---------------------------------------------------------------------------
__global__ __launch_bounds__(512) void attn_kernel(
    const float* __restrict__ qf2, const float* __restrict__ kT,
    const float* __restrict__ value,
    const int* __restrict__ jidx, const int* __restrict__ cntArr,
    const float* __restrict__ scale,
    float* __restrict__ out)
{
    const int r0 = blockIdx.x * 8;            // first query row (0..4095)
    const int b  = r0 >> 9;
    const int t  = threadIdx.x;               // 0..511

    __shared__ float q2[8 * Uu];              // 4 KB
    __shared__ float s2[Uu];                  // 0.5 KB
    __shared__ int   jl[Tv];                  // 2 KB
    __shared__ float w[8 * Tv];               // 16 KB
    __shared__ float pbuf[8 * Dd];            // 16 KB
    __shared__ float inv8[8];

    const int cnt = cntArr[b];

    jl[t] = jidx[b * Tv + t];
    if (t < 256)
        reinterpret_cast<float4*>(q2)[t] =
            reinterpret_cast<const float4*>(qf2 + (size_t)r0 * Uu)[t];
    else if (t < 384) s2[t - 256] = scale[t - 256];
    __syncthreads();

    // ---- scores over compact keys ----
    const int jc = t;
    if (jc < cnt) {
        const float* __restrict__ kb = kT + (size_t)b * Uu * Tv + jc;
        float acc[8] = {0,0,0,0,0,0,0,0};
#pragma unroll 2
        for (int u4 = 0; u4 < Uu / 4; ++u4) {
            const float kx = kb[(size_t)(u4 * 4 + 0) * Tv];
            const float ky = kb[(size_t)(u4 * 4 + 1) * Tv];
            const float kz = kb[(size_t)(u4 * 4 + 2) * Tv];
            const float kw = kb[(size_t)(u4 * 4 + 3) * Tv];
            const float4 sv = reinterpret_cast<const float4*>(s2)[u4];
#pragma unroll
            for (int i = 0; i < 8; ++i) {
                const float4 qv = *reinterpret_cast<const float4*>(q2 + i * Uu + u4 * 4);
                float e0 = __builtin_amdgcn_exp2f(qv.x + kx);
                float e1 = __builtin_amdgcn_exp2f(qv.y + ky);
                float e2 = __builtin_amdgcn_exp2f(qv.z + kz);
                float e3 = __builtin_amdgcn_exp2f(qv.w + kw);
                acc[i] = fmaf(sv.x, __builtin_amdgcn_rcpf(e0 + 1.f), acc[i]);
                acc[i] = fmaf(sv.y, __builtin_amdgcn_rcpf(e1 + 1.f), acc[i]);
                acc[i] = fmaf(sv.z, __builtin_amdgcn_rcpf(e2 + 1.f), acc[i]);
                acc[i] = fmaf(sv.w, __builtin_amdgcn_rcpf(e3 + 1.f), acc[i]);
            }
        }
#pragma unroll
        for (int i = 0; i < 8; ++i) w[i * Tv + jc] = -2.f * acc[i];
    } else {
#pragma unroll
        for (int i = 0; i < 8; ++i) w[i * Tv + jc] = 0.f;   // pad: weight 0
    }
    __syncthreads();

    // ---- softmax over [0,cnt): wave wv handles row wv ----
    {
        const int wv = t >> 6, ln = t & 63;
        float* __restrict__ row = w + wv * Tv;
        float vals[8];
        float m = -3e38f;
#pragma unroll
        for (int c = 0; c < 8; ++c) {
            const int e = ln + 64 * c;
            vals[c] = (e < cnt) ? row[e] : -3e38f;
            m = fmaxf(m, vals[c]);
        }
#pragma unroll
        for (int off = 32; off; off >>= 1) m = fmaxf(m, __shfl_xor(m, off, 64));
        float sum = 0.f;
#pragma unroll
        for (int c = 0; c < 8; ++c) {
            const int e = ln + 64 * c;
            if (e < cnt) {
                float ex = __builtin_amdgcn_exp2f((vals[c] - m) * LOG2E);
                row[e] = ex;
                sum += ex;
            }
        }
#pragma unroll
        for (int off = 32; off; off >>= 1) sum += __shfl_xor(sum, off, 64);
        if (ln == 0) inv8[wv] = 1.0f / sum;
    }
    __syncthreads();

    // ---- context over compact rows: group g owns a 4-aligned range ----
    const int cntp = (cnt + 3) & ~3;
    const int mid  = ((cntp >> 1) + 3) & ~3;
    const int g  = t >> 8;                 // 0/1
    const int c  = t & 255;
    const int d0 = c * 2;
    const int jbeg = g ? mid : 0;
    const int jend = g ? cntp : mid;
    const float* __restrict__ vb = value + (size_t)b * Tv * Dd + d0;
    float ax[8], ay[8];
#pragma unroll
    for (int i = 0; i < 8; ++i) { ax[i] = 0.f; ay[i] = 0.f; }

    for (int jj = jbeg; jj < jend; jj += 4) {
        const int4 rows = *reinterpret_cast<const int4*>(jl + jj);
        const float2 v0 = *reinterpret_cast<const float2*>(vb + (size_t)rows.x * Dd);
        const float2 v1 = *reinterpret_cast<const float2*>(vb + (size_t)rows.y * Dd);
        const float2 v2 = *reinterpret_cast<const float2*>(vb + (size_t)rows.z * Dd);
        const float2 v3 = *reinterpret_cast<const float2*>(vb + (size_t)rows.w * Dd);
#pragma unroll
        for (int i = 0; i < 8; ++i) {
            const float4 wq = *reinterpret_cast<const float4*>(w + i * Tv + jj); // broadcast
            ax[i] = fmaf(wq.x, v0.x, ax[i]); ay[i] = fmaf(wq.x, v0.y, ay[i]);
            ax[i] = fmaf(wq.y, v1.x, ax[i]); ay[i] = fmaf(wq.y, v1.y, ay[i]);
            ax[i] = fmaf(wq.z, v2.x, ax[i]); ay[i] = fmaf(wq.z, v2.y, ay[i]);
            ax[i] = fmaf(wq.w, v3.x, ax[i]); ay[i] = fmaf(wq.w, v3.y, ay[i]);
        }
    }

    if (g == 1) {
#pragma unroll
        for (int i = 0; i < 8; ++i) {
            float2 p; p.x = ax[i]; p.y = ay[i];
            *reinterpret_cast<float2*>(pbuf + i * Dd + d0) = p;
        }
    }
    __syncthreads();
    if (g == 0) {
#pragma unroll
        for (int i = 0; i < 8; ++i) {
            const float inv = inv8[i];
            const float2 p1 = *reinterpret_cast<const float2*>(pbuf + i * Dd + d0);
            float2 o;
            o.x = (ax[i] + p1.x) * inv;
            o.y = (ay[i] + p1.y) * inv;
            *reinterpret_cast<float2*>(out + (size_t)(r0 + i) * Dd + d0) = o;
        }
    }
}

extern "C" void kernel_launch(void* const* d_in, const int* in_sizes, int n_in,
                              void* d_out, int out_size, void* d_ws, size_t ws_size,
                              hipStream_t stream)
{
    const float* query = (const float*)d_in[0];
    const float* key   = (const float*)d_in[1];
    const float* value = (const float*)d_in[2];
    const int*   mask  = (const int*)d_in[3];     // proven int32 (R2 bit-identical)
    const float* Wa    = (const float*)d_in[4];
    const float* Ua    = (const float*)d_in[5];
    const float* scale = (const float*)d_in[6];
    float* out = (float*)d_out;

    float* qf2   = (float*)d_ws;                  // [4096,128] = 2 MB (premult)
    float* kT    = qf2 + Bb * Tq * Uu;            // [8][128][512] = 2 MB (compact)
    int* jidxW   = (int*)(kT + Bb * Uu * Tv);     // [8][512] 16 KB
    int* posArr  = jidxW + Bb * Tv;               // [8][512] 16 KB
    int* cntArr  = posArr + Bb * Tv;              // [8]

    compact_kernel<<<1, 512, 0, stream>>>(mask, jidxW, posArr, cntArr);
    proj_kernel<<<(2 * Bb * Tq) / 16, 256, 0, stream>>>(query, key, Wa, Ua, posArr, qf2, kT);
    attn_kernel<<<(Bb * Tq) / 8, 512, 0, stream>>>(qf2, kT, value, jidxW, cntArr, scale, out);
}